// Round 1
// baseline (1259.148 us; speedup 1.0000x reference)
//
#include <hip/hip_runtime.h>

// ---------------------------------------------------------------------------
// Structure_Diffusion: pooled-token attention gates + two gated 3x3 convs.
// Strategy:
//  - pool x1/x2 first (linearity), tiny GEMM for conv3/conv4+BN on 57 tokens
//  - attention + fc3 -> gates (8,256) per branch, all fp32 (tiny)
//  - 3x3 convs as implicit GEMM in bf16 MFMA over padded channels-last input
// ---------------------------------------------------------------------------

#define BATCH 8
#define CH    256
#define HH    96
#define WW    96
#define HWA   9216      // 96*96
#define NP    57
#define PH    98        // padded spatial
#define KTOT  2304      // 9*256
#define NCHUNK 72       // KTOT/32
#define IMGSZ (CH*HWA)  // per-batch-image elements (one channel-plane set)
#define OUTHALF (BATCH*CH*HWA)  // 18874368

typedef short  short8  __attribute__((ext_vector_type(8)));
typedef float  float4f __attribute__((ext_vector_type(4)));

__device__ __forceinline__ unsigned short f2bf(float f) {
    unsigned int u = __float_as_uint(f);
    u += 0x7fffu + ((u >> 16) & 1u);   // RNE
    return (unsigned short)(u >> 16);
}

// ---------------------------------------------------------------------------
// K1: pool x1/x2 into 57 block-means per (b,c).  grid (256 c, 8 b, 2 input)
// ---------------------------------------------------------------------------
__global__ void pool_kernel(const float* __restrict__ x1,
                            const float* __restrict__ x2,
                            float* __restrict__ px) {
    int c = blockIdx.x, b = blockIdx.y, z = blockIdx.z;
    const float* src = (z ? x2 : x1) + ((long)b * CH + c) * HWA;
    __shared__ float bins[144];       // 12x12 grid of 8x8 block sums
    int t = threadIdx.x;
    if (t < 144) bins[t] = 0.f;
    __syncthreads();
    for (int p = t; p < HWA; p += 256) {
        float v = src[p];
        int h = p / 96, w = p - h * 96;
        atomicAdd(&bins[(h >> 3) * 12 + (w >> 3)], v);
    }
    __syncthreads();
    if (t < NP) {
        int bh0, bw0, nb;
        if (t == 0)      { bh0 = 0; bw0 = 0; nb = 12; }
        else if (t < 5)  { int q = t - 1;  bh0 = (q >> 1) * 6; bw0 = (q & 1) * 6; nb = 6; }
        else if (t < 21) { int q = t - 5;  bh0 = (q >> 2) * 3; bw0 = (q & 3) * 3; nb = 3; }
        else             { int q = t - 21; bh0 = (q / 6) * 2;  bw0 = (q % 6) * 2; nb = 2; }
        float s = 0.f;
        for (int i = 0; i < nb; ++i)
            for (int j = 0; j < nb; ++j)
                s += bins[(bh0 + i) * 12 + (bw0 + j)];
        px[(((long)z * BATCH + b) * CH + c) * NP + t] = s / (float)(nb * nb * 64);
    }
}

// ---------------------------------------------------------------------------
// K2: y[z,b,n,c] = normalize_c( BN(conv1x1(px)) ).  grid (57 n, 8 b, 2 z)
// ---------------------------------------------------------------------------
__global__ void ycomp_kernel(const float* __restrict__ px,
    const float* __restrict__ w3, const float* __restrict__ cb3,
    const float* __restrict__ g3, const float* __restrict__ be3,
    const float* __restrict__ m3, const float* __restrict__ v3,
    const float* __restrict__ w4, const float* __restrict__ cb4,
    const float* __restrict__ g4, const float* __restrict__ be4,
    const float* __restrict__ m4, const float* __restrict__ v4,
    float* __restrict__ y) {
    int n = blockIdx.x, b = blockIdx.y, z = blockIdx.z;
    __shared__ float col[CH];
    __shared__ float red[CH];
    int c = threadIdx.x;
    col[c] = px[(((long)z * BATCH + b) * CH + c) * NP + n];
    __syncthreads();
    const float* w  = z ? w4  : w3;
    const float* cb = z ? cb4 : cb3;
    const float* gg = z ? g4  : g3;
    const float* be = z ? be4 : be3;
    const float* mm = z ? m4  : m3;
    const float* vv = z ? v4  : v3;
    float s = gg[c] * rsqrtf(vv[c] + 1e-5f);
    const float* wr = w + (long)c * CH;
    float acc = 0.f;
    for (int ci = 0; ci < CH; ++ci) acc += wr[ci] * col[ci];
    float yv = s * acc + (cb[c] - mm[c]) * s + be[c];
    red[c] = yv * yv;
    __syncthreads();
    for (int st = 128; st > 0; st >>= 1) {
        if (c < st) red[c] += red[c + st];
        __syncthreads();
    }
    float scale = 1.f / fmaxf(sqrtf(red[0]), 1e-12f);
    y[(((long)z * BATCH + b) * NP + n) * CH + c] = yv * scale;
}

// ---------------------------------------------------------------------------
// K3: per-batch attention + fc3 -> gates[2][8][256].  grid (8), 256 thr
// ---------------------------------------------------------------------------
__global__ void attn_kernel(const float* __restrict__ y,
    const float* __restrict__ fw1, const float* __restrict__ fb1,
    const float* __restrict__ fw2, const float* __restrict__ fb2,
    const float* __restrict__ w31, const float* __restrict__ b31,
    const float* __restrict__ w32, const float* __restrict__ b32,
    float* __restrict__ gates) {
    int b = blockIdx.x, t = threadIdx.x;
    __shared__ float y1s[NP * 257];    // padded row stride (bank spread)
    __shared__ float y2s[NP * 257];
    __shared__ float l1[NP * NP];
    __shared__ float l2[NP * NP];
    __shared__ float w31s[16 * NP];
    const float* y1g = y + (long)b * NP * CH;
    const float* y2g = y + (long)(BATCH + b) * NP * CH;
    for (int i = t; i < NP * CH; i += 256) {
        int n = i >> 8, c = i & 255;
        y1s[n * 257 + c] = y1g[i];
        y2s[n * 257 + c] = y2g[i];
    }
    for (int i = t; i < 16 * NP; i += 256) w31s[i] = w31[i];
    __syncthreads();
    float a10 = fw1[0], a11 = fw1[1], a12 = fw1[2], a13 = fw1[3], b1v = fb1[0];
    float a20 = fw2[0], a21 = fw2[1], a22 = fw2[2], a23 = fw2[3], b2v = fb2[0];
    for (int idx = t; idx < NP * NP; idx += 256) {
        int n = idx / NP, m = idx - n * NP;
        const float* yn1 = y1s + n * 257;
        const float* ym1 = y1s + m * 257;
        const float* yn2 = y2s + n * 257;
        const float* ym2 = y2s + m * 257;
        float d1 = 0.f, d2 = 0.f, d12 = 0.f;
        for (int c = 0; c < CH; ++c) {
            d1  += yn1[c] * ym1[c];
            d2  += yn2[c] * ym2[c];
            d12 += yn1[c] * ym2[c];
        }
        float s1 = 1.f - d1, s2 = 1.f - d2, s12 = 1.f - d12;
        l1[idx] = a10 * s1 + a11 * s2 + a12 * s1 * s2 + a13 * s12 + b1v;
        l2[idx] = a20 * s1 + a21 * s2 + a22 * s1 * s2 + a23 * s12 + b2v;
    }
    __syncthreads();
    if (t < 2 * NP) {    // softmax rows (both branches)
        int which = t >= NP;
        int n = which ? t - NP : t;
        float* l = which ? l2 : l1;
        float mx = -1e30f;
        for (int m = 0; m < NP; ++m) mx = fmaxf(mx, l[n * NP + m]);
        float sum = 0.f;
        for (int m = 0; m < NP; ++m) { float e = __expf(l[n * NP + m] - mx); l[n * NP + m] = e; sum += e; }
        float inv = 1.f / sum;
        for (int m = 0; m < NP; ++m) l[n * NP + m] *= inv;
    }
    __syncthreads();
    int c = t;
    float h1[16], h2[16];
#pragma unroll
    for (int k = 0; k < 16; ++k) { h1[k] = 0.f; h2[k] = 0.f; }
    for (int n = 0; n < NP; ++n) {
        float g1 = 0.f, g2 = 0.f;
        for (int m = 0; m < NP; ++m) {
            g1 += l1[n * NP + m] * y1s[m * 257 + c];
            g2 += l2[n * NP + m] * y2s[m * 257 + c];
        }
#pragma unroll
        for (int k = 0; k < 16; ++k) {
            float wv = w31s[k * NP + n];
            h1[k] += wv * g1;
            h2[k] += wv * g2;
        }
    }
    float o1 = b32[0], o2 = b32[0];
#pragma unroll
    for (int k = 0; k < 16; ++k) {
        float wk = w32[k];
        o1 += wk * (h1[k] + b31[k]);
        o2 += wk * (h2[k] + b31[k]);
    }
    gates[b * CH + c]                = 1.f / (1.f + __expf(-o1));
    gates[2048 + b * CH + c]         = 1.f / (1.f + __expf(-o2));
}

// ---------------------------------------------------------------------------
// K4: prepack conv1/conv2 weights (BN scale folded) -> Wp[which][co][k] bf16,
//     k = (3*dy+dx)*256 + ci; also fold bias.  grid 4608 x 256
// ---------------------------------------------------------------------------
__global__ void prepack_kernel(
    const float* __restrict__ w1, const float* __restrict__ cb1,
    const float* __restrict__ g1, const float* __restrict__ be1,
    const float* __restrict__ m1, const float* __restrict__ v1,
    const float* __restrict__ w2, const float* __restrict__ cb2,
    const float* __restrict__ g2, const float* __restrict__ be2,
    const float* __restrict__ m2, const float* __restrict__ v2,
    unsigned short* __restrict__ Wp, float* __restrict__ bias) {
    long idx = (long)blockIdx.x * 256 + threadIdx.x;   // 0 .. 2*256*2304-1
    int which = idx >= (long)CH * KTOT;
    long rem = idx - (long)which * CH * KTOT;
    int co = (int)(rem / KTOT);
    int k  = (int)(rem - (long)co * KTOT);
    int r = k >> 8, ci = k & 255;
    int dy = r / 3, dx = r - dy * 3;
    const float* w  = which ? w2  : w1;
    const float* cb = which ? cb2 : cb1;
    const float* gg = which ? g2  : g1;
    const float* be = which ? be2 : be1;
    const float* mm = which ? m2  : m1;
    const float* vv = which ? v2  : v1;
    float s = gg[co] * rsqrtf(vv[co] + 1e-5f);
    float val = w[(((long)co * CH + ci) * 3 + dy) * 3 + dx] * s;
    Wp[idx] = f2bf(val);
    if (k == 0) bias[which * CH + co] = (cb[co] - mm[co]) * s + be[co];
}

// ---------------------------------------------------------------------------
// K5: pad+transpose x3/x4 -> channels-last padded bf16 (8,98,98,256).
//     grid (98 hp, 8 b, 2 which)
// ---------------------------------------------------------------------------
__global__ void pad_kernel(const float* __restrict__ x3,
                           const float* __restrict__ x4,
                           unsigned short* __restrict__ xp3,
                           unsigned short* __restrict__ xp4) {
    int hp = blockIdx.x, b = blockIdx.y, z = blockIdx.z;
    const float* src = z ? x4 : x3;
    unsigned short* dst = z ? xp4 : xp3;
    __shared__ float buf[64][97];
    int t = threadIdx.x;
    bool border = (hp == 0 || hp == PH - 1);
    int h = hp - 1;
    for (int ci0 = 0; ci0 < CH; ci0 += 64) {
        if (!border) {
            for (int idx = t; idx < 64 * 96; idx += 256) {
                int cl = idx / 96, w = idx - cl * 96;
                buf[cl][w] = src[(((long)b * CH + ci0 + cl) * HH + h) * WW + w];
            }
        }
        __syncthreads();
        for (int idx = t; idx < PH * 64; idx += 256) {
            int wp = idx >> 6, cl = idx & 63;
            float v = 0.f;
            if (!border && wp >= 1 && wp <= 96) v = buf[cl][wp - 1];
            dst[(((long)b * PH + hp) * PH + wp) * CH + ci0 + cl] = f2bf(v);
        }
        __syncthreads();
    }
}

// ---------------------------------------------------------------------------
// K6: gated 3x3 conv as implicit bf16 MFMA GEMM.
//   M-tile = 8 rows x 16 cols (128 pixels), N-tile = 128 co, BK = 32.
//   grid (576 m-tiles, 2 n-tiles); 256 threads = 4 waves (2x2 of 64x64).
//   out = resid + gate[b,co] * (acc + bias[co])
// ---------------------------------------------------------------------------
__global__ __launch_bounds__(256)
void conv_gemm(const unsigned short* __restrict__ xp,
               const unsigned short* __restrict__ Wp,
               const float* __restrict__ gate,
               const float* __restrict__ bias,
               const float* __restrict__ resid,
               float* __restrict__ out) {
    // LDS: [quad][row][8 bf16] -> ds_read_b128-friendly, conflict-free
    __shared__ short As[4 * 128 * 8];
    __shared__ short Bs[4 * 128 * 8];
    int tid = threadIdx.x;
    int bm = blockIdx.x, co0 = blockIdx.y * 128;
    int bimg = bm / 72, tt = bm - bimg * 72;
    int h0 = (tt / 6) * 8, w0 = (tt % 6) * 16;

    // staging ids (each thread stages 32B of A and 32B of B per chunk)
    int spm = tid >> 1, shalf = tid & 1;
    int prow = spm >> 4, pcol = spm & 15;
    long abase = (((long)(bimg * PH + h0 + prow)) * PH + (w0 + pcol)) * CH + shalf * 16;
    long bbase = (long)(co0 + spm) * KTOT + shalf * 16;
    int qa = shalf * 2;  // destination quad pair

    // compute ids
    int lane = tid & 63, wid = tid >> 6;
    int wm = wid & 1, wn = wid >> 1;
    int lm = lane & 15, quad = lane >> 4;

    float4f acc[4][4] = {};

    for (int kc = 0; kc < NCHUNK; ++kc) {
        int r = kc >> 3, ci0 = (kc & 7) << 5;
        int dy = r / 3, dx = r - dy * 3;
        __syncthreads();
        const short8* ga = (const short8*)(xp + abase + (long)(dy * PH + dx) * CH + ci0);
        short8 va0 = ga[0];
        short8 va1 = ga[1];
        const short8* gb = (const short8*)(Wp + bbase + r * 256 + ci0);
        short8 vb0 = gb[0];
        short8 vb1 = gb[1];
        *(short8*)&As[(qa    ) * 1024 + spm * 8] = va0;
        *(short8*)&As[(qa + 1) * 1024 + spm * 8] = va1;
        *(short8*)&Bs[(qa    ) * 1024 + spm * 8] = vb0;
        *(short8*)&Bs[(qa + 1) * 1024 + spm * 8] = vb1;
        __syncthreads();
        short8 af[4], bfr[4];
#pragma unroll
        for (int i = 0; i < 4; ++i)
            af[i] = *(short8*)&As[quad * 1024 + (wm * 64 + i * 16 + lm) * 8];
#pragma unroll
        for (int j = 0; j < 4; ++j)
            bfr[j] = *(short8*)&Bs[quad * 1024 + (wn * 64 + j * 16 + lm) * 8];
#pragma unroll
        for (int i = 0; i < 4; ++i)
#pragma unroll
            for (int j = 0; j < 4; ++j)
                acc[i][j] = __builtin_amdgcn_mfma_f32_16x16x32_bf16(af[i], bfr[j], acc[i][j], 0, 0, 0);
    }

    // epilogue: D row = quad*4+reg (pixel w-offset), col = lane&15 (co)
#pragma unroll
    for (int j = 0; j < 4; ++j) {
        int co = co0 + wn * 64 + j * 16 + lm;
        float g  = gate[bimg * CH + co];
        float bv = bias[co];
#pragma unroll
        for (int i = 0; i < 4; ++i) {
            int h = h0 + wm * 4 + i;
            int w = w0 + quad * 4;
            long o = ((long)(bimg * CH + co)) * HWA + h * WW + w;
            float4f rv = *(const float4f*)(resid + o);
            float4f ov = rv + g * (acc[i][j] + bv);
            *(float4f*)(out + o) = ov;
        }
    }
}

// ---------------------------------------------------------------------------
extern "C" void kernel_launch(void* const* d_in, const int* in_sizes, int n_in,
                              void* d_out, int out_size, void* d_ws, size_t ws_size,
                              hipStream_t stream) {
    const float* x1 = (const float*)d_in[0];
    const float* x2 = (const float*)d_in[1];
    const float* x3 = (const float*)d_in[2];
    const float* x4 = (const float*)d_in[3];
    const float* conv3_w = (const float*)d_in[4];
    const float* conv3_b = (const float*)d_in[5];
    const float* bn3_g = (const float*)d_in[6];
    const float* bn3_b = (const float*)d_in[7];
    const float* bn3_m = (const float*)d_in[8];
    const float* bn3_v = (const float*)d_in[9];
    const float* conv4_w = (const float*)d_in[10];
    const float* conv4_b = (const float*)d_in[11];
    const float* bn4_g = (const float*)d_in[12];
    const float* bn4_b = (const float*)d_in[13];
    const float* bn4_m = (const float*)d_in[14];
    const float* bn4_v = (const float*)d_in[15];
    const float* conv1_w = (const float*)d_in[16];
    const float* conv1_b = (const float*)d_in[17];
    const float* bn1_g = (const float*)d_in[18];
    const float* bn1_b = (const float*)d_in[19];
    const float* bn1_m = (const float*)d_in[20];
    const float* bn1_v = (const float*)d_in[21];
    const float* conv2_w = (const float*)d_in[22];
    const float* conv2_b = (const float*)d_in[23];
    const float* bn2_g = (const float*)d_in[24];
    const float* bn2_b = (const float*)d_in[25];
    const float* bn2_m = (const float*)d_in[26];
    const float* bn2_v = (const float*)d_in[27];
    const float* fc1_w = (const float*)d_in[28];
    const float* fc1_b = (const float*)d_in[29];
    const float* fc2_w = (const float*)d_in[30];
    const float* fc2_b = (const float*)d_in[31];
    const float* fc3_w1 = (const float*)d_in[32];
    const float* fc3_b1 = (const float*)d_in[33];
    const float* fc3_w2 = (const float*)d_in[34];
    const float* fc3_b2 = (const float*)d_in[35];

    float* ws = (float*)d_ws;
    float* px    = ws;                 // 2*8*256*57   = 233472 floats
    float* y     = ws + 233472;        // 233472 floats
    float* gates = ws + 466944;        // 2*8*256 = 4096
    float* bias  = ws + 471040;        // 2*256 = 512
    unsigned short* Wp  = (unsigned short*)(ws + 471552);   // 2*256*2304 shorts
    unsigned short* xp3 = Wp + 2 * CH * KTOT;               // 8*98*98*256 shorts
    unsigned short* xp4 = xp3 + (long)BATCH * PH * PH * CH;

    pool_kernel<<<dim3(256, 8, 2), 256, 0, stream>>>(x1, x2, px);
    ycomp_kernel<<<dim3(57, 8, 2), 256, 0, stream>>>(px,
        conv3_w, conv3_b, bn3_g, bn3_b, bn3_m, bn3_v,
        conv4_w, conv4_b, bn4_g, bn4_b, bn4_m, bn4_v, y);
    attn_kernel<<<dim3(8), 256, 0, stream>>>(y, fc1_w, fc1_b, fc2_w, fc2_b,
        fc3_w1, fc3_b1, fc3_w2, fc3_b2, gates);
    prepack_kernel<<<dim3(4608), 256, 0, stream>>>(
        conv1_w, conv1_b, bn1_g, bn1_b, bn1_m, bn1_v,
        conv2_w, conv2_b, bn2_g, bn2_b, bn2_m, bn2_v, Wp, bias);
    pad_kernel<<<dim3(PH, 8, 2), 256, 0, stream>>>(x3, x4, xp3, xp4);

    // x3_out = x3 + gate1 * BN1(conv1(x4));  x4_out = x4 + gate2 * BN2(conv2(x3))
    conv_gemm<<<dim3(576, 2), 256, 0, stream>>>(xp4, Wp, gates, bias,
        x3, (float*)d_out);
    conv_gemm<<<dim3(576, 2), 256, 0, stream>>>(xp3, Wp + (long)CH * KTOT,
        gates + 2048, bias + CH, x4, (float*)d_out + OUTHALF);
}

// Round 2
// 1086.834 us; speedup vs baseline: 1.1585x; 1.1585x over previous
//
#include <hip/hip_runtime.h>

// ---------------------------------------------------------------------------
// Structure_Diffusion: pooled-token attention gates + two gated 3x3 convs.
//  - pool-first (linearity) -> conv3/conv4+BN on 57 tokens only
//  - attention + fc3 -> gates (2,8,256), fp32 (tiny)
//  - 3x3 convs as implicit bf16 MFMA GEMM, channels-last padded input,
//    async global->LDS staging (global_load_lds width=16)
// ---------------------------------------------------------------------------

#define BATCH 8
#define CH    256
#define HH    96
#define WW    96
#define HWA   9216      // 96*96
#define NP    57
#define PH    98        // padded spatial
#define KTOT  2304      // 9*256
#define NCHUNK 72       // KTOT/32
#define OUTHALF (BATCH*CH*HWA)  // 18874368

typedef short  short8  __attribute__((ext_vector_type(8)));
typedef float  float4f __attribute__((ext_vector_type(4)));
typedef unsigned short us4 __attribute__((ext_vector_type(4)));

__device__ __forceinline__ unsigned short f2bf(float f) {
    unsigned int u = __float_as_uint(f);
    u += 0x7fffu + ((u >> 16) & 1u);   // RNE
    return (unsigned short)(u >> 16);
}

#define GLDS16(gp, sp) __builtin_amdgcn_global_load_lds( \
    (const __attribute__((address_space(1))) void*)(gp),  \
    (__attribute__((address_space(3))) void*)(sp), 16, 0, 0)

// ---------------------------------------------------------------------------
// K1: pool x1/x2 into 57 block-means per (b,c).  grid (256 c, 8 b, 2 input)
// Atomic-free: per-thread 8-float segment sums -> LDS -> tree to 12x12 bins.
// ---------------------------------------------------------------------------
__global__ void pool_kernel(const float* __restrict__ x1,
                            const float* __restrict__ x2,
                            float* __restrict__ px) {
    int c = blockIdx.x, b = blockIdx.y, z = blockIdx.z;
    const float* src = (z ? x2 : x1) + ((long)b * CH + c) * HWA;
    __shared__ float seg[1152];   // [row 96][colblock 12]
    __shared__ float bins[144];   // 12x12 grid of 8x8 block sums
    int t = threadIdx.x;
    for (int s = t; s < 1152; s += 256) {
        int r = s / 12, cb = s - r * 12;
        const float4f* p = (const float4f*)(src + r * 96 + cb * 8);
        float4f a = p[0], bv = p[1];
        seg[s] = (a.x + a.y) + (a.z + a.w) + (bv.x + bv.y) + (bv.z + bv.w);
    }
    __syncthreads();
    if (t < 144) {
        int i = t / 12, j = t - i * 12;
        float s = 0.f;
#pragma unroll
        for (int r = 0; r < 8; ++r) s += seg[(i * 8 + r) * 12 + j];
        bins[t] = s;
    }
    __syncthreads();
    if (t < NP) {
        int bh0, bw0, nb;
        if (t == 0)      { bh0 = 0; bw0 = 0; nb = 12; }
        else if (t < 5)  { int q = t - 1;  bh0 = (q >> 1) * 6; bw0 = (q & 1) * 6; nb = 6; }
        else if (t < 21) { int q = t - 5;  bh0 = (q >> 2) * 3; bw0 = (q & 3) * 3; nb = 3; }
        else             { int q = t - 21; bh0 = (q / 6) * 2;  bw0 = (q % 6) * 2; nb = 2; }
        float s = 0.f;
        for (int i = 0; i < nb; ++i)
            for (int j = 0; j < nb; ++j)
                s += bins[(bh0 + i) * 12 + (bw0 + j)];
        px[(((long)z * BATCH + b) * CH + c) * NP + t] = s / (float)(nb * nb * 64);
    }
}

// ---------------------------------------------------------------------------
// K2: y[z,b,n,c] = normalize_c( BN(conv1x1(px)) ).  grid (57 n, 8 b, 2 z)
// ---------------------------------------------------------------------------
__global__ void ycomp_kernel(const float* __restrict__ px,
    const float* __restrict__ w3, const float* __restrict__ cb3,
    const float* __restrict__ g3, const float* __restrict__ be3,
    const float* __restrict__ m3, const float* __restrict__ v3,
    const float* __restrict__ w4, const float* __restrict__ cb4,
    const float* __restrict__ g4, const float* __restrict__ be4,
    const float* __restrict__ m4, const float* __restrict__ v4,
    float* __restrict__ y) {
    int n = blockIdx.x, b = blockIdx.y, z = blockIdx.z;
    __shared__ float col[CH];
    __shared__ float red[CH];
    int c = threadIdx.x;
    col[c] = px[(((long)z * BATCH + b) * CH + c) * NP + n];
    __syncthreads();
    const float* w  = z ? w4  : w3;
    const float* cb = z ? cb4 : cb3;
    const float* gg = z ? g4  : g3;
    const float* be = z ? be4 : be3;
    const float* mm = z ? m4  : m3;
    const float* vv = z ? v4  : v3;
    float s = gg[c] * rsqrtf(vv[c] + 1e-5f);
    const float4f* wr4  = (const float4f*)(w + (long)c * CH);
    const float4f* col4 = (const float4f*)col;
    float4f a4 = {0.f, 0.f, 0.f, 0.f};
#pragma unroll 8
    for (int ci = 0; ci < CH / 4; ++ci) a4 += wr4[ci] * col4[ci];
    float acc = (a4.x + a4.y) + (a4.z + a4.w);
    float yv = s * acc + (cb[c] - mm[c]) * s + be[c];
    red[c] = yv * yv;
    __syncthreads();
    for (int st = 128; st > 0; st >>= 1) {
        if (c < st) red[c] += red[c + st];
        __syncthreads();
    }
    float scale = 1.f / fmaxf(sqrtf(red[0]), 1e-12f);
    y[(((long)z * BATCH + b) * NP + n) * CH + c] = yv * scale;
}

// ---------------------------------------------------------------------------
// K3: per-batch attention + fc3 -> gates[2][8][256].  grid (8), 256 thr
// ---------------------------------------------------------------------------
__global__ void attn_kernel(const float* __restrict__ y,
    const float* __restrict__ fw1, const float* __restrict__ fb1,
    const float* __restrict__ fw2, const float* __restrict__ fb2,
    const float* __restrict__ w31, const float* __restrict__ b31,
    const float* __restrict__ w32, const float* __restrict__ b32,
    float* __restrict__ gates) {
    int b = blockIdx.x, t = threadIdx.x;
    __shared__ float y1s[NP * 257];    // padded row stride (bank spread)
    __shared__ float y2s[NP * 257];
    __shared__ float l1[NP * NP];
    __shared__ float l2[NP * NP];
    __shared__ float w31s[16 * NP];
    const float* y1g = y + (long)b * NP * CH;
    const float* y2g = y + (long)(BATCH + b) * NP * CH;
    for (int i = t; i < NP * CH; i += 256) {
        int n = i >> 8, c = i & 255;
        y1s[n * 257 + c] = y1g[i];
        y2s[n * 257 + c] = y2g[i];
    }
    for (int i = t; i < 16 * NP; i += 256) w31s[i] = w31[i];
    __syncthreads();
    float a10 = fw1[0], a11 = fw1[1], a12 = fw1[2], a13 = fw1[3], b1v = fb1[0];
    float a20 = fw2[0], a21 = fw2[1], a22 = fw2[2], a23 = fw2[3], b2v = fb2[0];
    for (int idx = t; idx < NP * NP; idx += 256) {
        int n = idx / NP, m = idx - n * NP;
        const float* yn1 = y1s + n * 257;
        const float* ym1 = y1s + m * 257;
        const float* yn2 = y2s + n * 257;
        const float* ym2 = y2s + m * 257;
        float d1 = 0.f, d2 = 0.f, d12 = 0.f;
        for (int c = 0; c < CH; ++c) {
            d1  += yn1[c] * ym1[c];
            d2  += yn2[c] * ym2[c];
            d12 += yn1[c] * ym2[c];
        }
        float s1 = 1.f - d1, s2 = 1.f - d2, s12 = 1.f - d12;
        l1[idx] = a10 * s1 + a11 * s2 + a12 * s1 * s2 + a13 * s12 + b1v;
        l2[idx] = a20 * s1 + a21 * s2 + a22 * s1 * s2 + a23 * s12 + b2v;
    }
    __syncthreads();
    if (t < 2 * NP) {    // softmax rows (both branches)
        int which = t >= NP;
        int n = which ? t - NP : t;
        float* l = which ? l2 : l1;
        float mx = -1e30f;
        for (int m = 0; m < NP; ++m) mx = fmaxf(mx, l[n * NP + m]);
        float sum = 0.f;
        for (int m = 0; m < NP; ++m) { float e = __expf(l[n * NP + m] - mx); l[n * NP + m] = e; sum += e; }
        float inv = 1.f / sum;
        for (int m = 0; m < NP; ++m) l[n * NP + m] *= inv;
    }
    __syncthreads();
    int c = t;
    float h1[16], h2[16];
#pragma unroll
    for (int k = 0; k < 16; ++k) { h1[k] = 0.f; h2[k] = 0.f; }
    for (int n = 0; n < NP; ++n) {
        float g1 = 0.f, g2 = 0.f;
        for (int m = 0; m < NP; ++m) {
            g1 += l1[n * NP + m] * y1s[m * 257 + c];
            g2 += l2[n * NP + m] * y2s[m * 257 + c];
        }
#pragma unroll
        for (int k = 0; k < 16; ++k) {
            float wv = w31s[k * NP + n];
            h1[k] += wv * g1;
            h2[k] += wv * g2;
        }
    }
    float o1 = b32[0], o2 = b32[0];
#pragma unroll
    for (int k = 0; k < 16; ++k) {
        float wk = w32[k];
        o1 += wk * (h1[k] + b31[k]);
        o2 += wk * (h2[k] + b31[k]);
    }
    gates[b * CH + c]        = 1.f / (1.f + __expf(-o1));
    gates[2048 + b * CH + c] = 1.f / (1.f + __expf(-o2));
}

// ---------------------------------------------------------------------------
// K4: prepack conv1/conv2 weights (BN scale folded) -> Wp[which][co][k] bf16,
//     k = (3*dy+dx)*256 + ci; also fold bias.  grid 4608 x 256
// ---------------------------------------------------------------------------
__global__ void prepack_kernel(
    const float* __restrict__ w1, const float* __restrict__ cb1,
    const float* __restrict__ g1, const float* __restrict__ be1,
    const float* __restrict__ m1, const float* __restrict__ v1,
    const float* __restrict__ w2, const float* __restrict__ cb2,
    const float* __restrict__ g2, const float* __restrict__ be2,
    const float* __restrict__ m2, const float* __restrict__ v2,
    unsigned short* __restrict__ Wp, float* __restrict__ bias) {
    long idx = (long)blockIdx.x * 256 + threadIdx.x;   // 0 .. 2*256*2304-1
    int which = idx >= (long)CH * KTOT;
    long rem = idx - (long)which * CH * KTOT;
    int co = (int)(rem / KTOT);
    int k  = (int)(rem - (long)co * KTOT);
    int r = k >> 8, ci = k & 255;
    int dy = r / 3, dx = r - dy * 3;
    const float* w  = which ? w2  : w1;
    const float* cb = which ? cb2 : cb1;
    const float* gg = which ? g2  : g1;
    const float* be = which ? be2 : be1;
    const float* mm = which ? m2  : m1;
    const float* vv = which ? v2  : v1;
    float s = gg[co] * rsqrtf(vv[co] + 1e-5f);
    float val = w[(((long)co * CH + ci) * 3 + dy) * 3 + dx] * s;
    Wp[idx] = f2bf(val);
    if (k == 0) bias[which * CH + co] = (cb[co] - mm[co]) * s + be[co];
}

// ---------------------------------------------------------------------------
// K5: pad+transpose x3/x4 -> channels-last padded bf16 (8,98,98,256).
//     grid (98 hp, 8 b, 2 which).  ushort4 (8B/lane) writes.
// ---------------------------------------------------------------------------
__global__ void pad_kernel(const float* __restrict__ x3,
                           const float* __restrict__ x4,
                           unsigned short* __restrict__ xp3,
                           unsigned short* __restrict__ xp4) {
    int hp = blockIdx.x, b = blockIdx.y, z = blockIdx.z;
    const float* src = z ? x4 : x3;
    unsigned short* dst = z ? xp4 : xp3;
    __shared__ float buf[64][97];
    int t = threadIdx.x;
    bool border = (hp == 0 || hp == PH - 1);
    int h = hp - 1;
    for (int ci0 = 0; ci0 < CH; ci0 += 64) {
        if (!border) {
            for (int idx = t; idx < 64 * 96; idx += 256) {
                int cl = idx / 96, w = idx - cl * 96;
                buf[cl][w] = src[(((long)b * CH + ci0 + cl) * HH + h) * WW + w];
            }
        }
        __syncthreads();
        for (int idx = t; idx < PH * 16; idx += 256) {
            int wp = idx >> 4, cq = idx & 15;
            us4 v = {0, 0, 0, 0};
            if (!border && wp >= 1 && wp <= 96) {
                int wq = wp - 1;
                v.x = f2bf(buf[cq * 4 + 0][wq]);
                v.y = f2bf(buf[cq * 4 + 1][wq]);
                v.z = f2bf(buf[cq * 4 + 2][wq]);
                v.w = f2bf(buf[cq * 4 + 3][wq]);
            }
            *(us4*)&dst[(((long)b * PH + hp) * PH + wp) * CH + ci0 + cq * 4] = v;
        }
        __syncthreads();
    }
}

// ---------------------------------------------------------------------------
// K6: gated 3x3 conv as implicit bf16 MFMA GEMM, async LDS staging.
//   M-tile = 8 rows x 16 cols (128 pixels), N-tile = 128 co, BK = 32.
//   grid (576 m-tiles, 2 n-tiles, 2 conv); 256 threads = 4 waves.
//   out = resid + gate[b,co] * (acc + bias[co])
// ---------------------------------------------------------------------------
__global__ __launch_bounds__(256)
void conv_gemm(const unsigned short* __restrict__ xp3,
               const unsigned short* __restrict__ xp4,
               const unsigned short* __restrict__ Wp0,
               const float* __restrict__ gates,
               const float* __restrict__ bias2,
               const float* __restrict__ x3,
               const float* __restrict__ x4,
               float* __restrict__ outg) {
    int zc = blockIdx.z;
    const unsigned short* xp = zc ? xp3 : xp4;
    const unsigned short* Wp = Wp0 + (long)zc * CH * KTOT;
    const float* gate  = gates + (long)zc * 2048;
    const float* bias  = bias2 + zc * CH;
    const float* resid = zc ? x4 : x3;
    float* out = outg + (long)zc * OUTHALF;

    // LDS: [quad][row][8 bf16] -> ds_read_b128-friendly, conflict-free
    __shared__ short As[4 * 128 * 8];
    __shared__ short Bs[4 * 128 * 8];
    int tid = threadIdx.x;
    int bm = blockIdx.x, co0 = blockIdx.y * 128;
    int bimg = bm / 72, tt = bm - bimg * 72;
    int h0 = (tt / 6) * 8, w0 = (tt % 6) * 16;

    int lane = tid & 63, wid = tid >> 6;
    int wm = wid & 1, wn = wid >> 1;
    int lm = lane & 15, quad = lane >> 4;

    // staging: wave `wid` owns quad `wid` of both A and B LDS tiles.
    // instruction half ∈ {0,1}: rows/cos 64*half + lane.
    int ar0 = lane, ar1 = 64 + lane;                  // A rows (pixels)
    long apix0 = ((long)(bimg * PH + h0 + (ar0 >> 4)) * PH + (w0 + (ar0 & 15))) * CH + wid * 8;
    long apix1 = ((long)(bimg * PH + h0 + (ar1 >> 4)) * PH + (w0 + (ar1 & 15))) * CH + wid * 8;
    long bb0 = (long)(co0 + lane) * KTOT + wid * 8;
    long bb1 = (long)(co0 + 64 + lane) * KTOT + wid * 8;
    short* asd0 = &As[wid * 1024];         // + half*512 (wave-uniform)
    short* asd1 = &As[wid * 1024 + 512];
    short* bsd0 = &Bs[wid * 1024];
    short* bsd1 = &Bs[wid * 1024 + 512];

    float4f acc[4][4] = {};

    for (int kc = 0; kc < NCHUNK; ++kc) {
        int r9 = kc >> 3;
        int dy = r9 / 3, dx = r9 - dy * 3;
        long aoff = (long)(dy * PH + dx) * CH + ((kc & 7) << 5);
        long boff = (long)kc << 5;
        __syncthreads();
        GLDS16(xp + apix0 + aoff, asd0);
        GLDS16(xp + apix1 + aoff, asd1);
        GLDS16(Wp + bb0 + boff, bsd0);
        GLDS16(Wp + bb1 + boff, bsd1);
        __syncthreads();
        short8 af[4], bfr[4];
#pragma unroll
        for (int i = 0; i < 4; ++i)
            af[i] = *(short8*)&As[quad * 1024 + (wm * 64 + i * 16 + lm) * 8];
#pragma unroll
        for (int j = 0; j < 4; ++j)
            bfr[j] = *(short8*)&Bs[quad * 1024 + (wn * 64 + j * 16 + lm) * 8];
#pragma unroll
        for (int i = 0; i < 4; ++i)
#pragma unroll
            for (int j = 0; j < 4; ++j)
                acc[i][j] = __builtin_amdgcn_mfma_f32_16x16x32_bf16(af[i], bfr[j], acc[i][j], 0, 0, 0);
    }

    // epilogue: D row = quad*4+reg (pixel w-offset), col = lane&15 (co)
#pragma unroll
    for (int j = 0; j < 4; ++j) {
        int co = co0 + wn * 64 + j * 16 + lm;
        float g  = gate[bimg * CH + co];
        float bv = bias[co];
#pragma unroll
        for (int i = 0; i < 4; ++i) {
            int h = h0 + wm * 4 + i;
            int w = w0 + quad * 4;
            long o = ((long)(bimg * CH + co)) * HWA + h * WW + w;
            float4f rv = *(const float4f*)(resid + o);
            float4f ov = rv + g * (acc[i][j] + bv);
            *(float4f*)(out + o) = ov;
        }
    }
}

// ---------------------------------------------------------------------------
extern "C" void kernel_launch(void* const* d_in, const int* in_sizes, int n_in,
                              void* d_out, int out_size, void* d_ws, size_t ws_size,
                              hipStream_t stream) {
    const float* x1 = (const float*)d_in[0];
    const float* x2 = (const float*)d_in[1];
    const float* x3 = (const float*)d_in[2];
    const float* x4 = (const float*)d_in[3];
    const float* conv3_w = (const float*)d_in[4];
    const float* conv3_b = (const float*)d_in[5];
    const float* bn3_g = (const float*)d_in[6];
    const float* bn3_b = (const float*)d_in[7];
    const float* bn3_m = (const float*)d_in[8];
    const float* bn3_v = (const float*)d_in[9];
    const float* conv4_w = (const float*)d_in[10];
    const float* conv4_b = (const float*)d_in[11];
    const float* bn4_g = (const float*)d_in[12];
    const float* bn4_b = (const float*)d_in[13];
    const float* bn4_m = (const float*)d_in[14];
    const float* bn4_v = (const float*)d_in[15];
    const float* conv1_w = (const float*)d_in[16];
    const float* conv1_b = (const float*)d_in[17];
    const float* bn1_g = (const float*)d_in[18];
    const float* bn1_b = (const float*)d_in[19];
    const float* bn1_m = (const float*)d_in[20];
    const float* bn1_v = (const float*)d_in[21];
    const float* conv2_w = (const float*)d_in[22];
    const float* conv2_b = (const float*)d_in[23];
    const float* bn2_g = (const float*)d_in[24];
    const float* bn2_b = (const float*)d_in[25];
    const float* bn2_m = (const float*)d_in[26];
    const float* bn2_v = (const float*)d_in[27];
    const float* fc1_w = (const float*)d_in[28];
    const float* fc1_b = (const float*)d_in[29];
    const float* fc2_w = (const float*)d_in[30];
    const float* fc2_b = (const float*)d_in[31];
    const float* fc3_w1 = (const float*)d_in[32];
    const float* fc3_b1 = (const float*)d_in[33];
    const float* fc3_w2 = (const float*)d_in[34];
    const float* fc3_b2 = (const float*)d_in[35];

    float* ws = (float*)d_ws;
    float* px    = ws;                 // 2*8*256*57 = 233472 floats
    float* y     = ws + 233472;        // 233472 floats
    float* gates = ws + 466944;        // 2*8*256 = 4096
    float* bias  = ws + 471040;        // 2*256 = 512
    unsigned short* Wp  = (unsigned short*)(ws + 471552);   // 2*256*2304 shorts
    unsigned short* xp3 = Wp + 2 * CH * KTOT;               // 8*98*98*256 shorts
    unsigned short* xp4 = xp3 + (long)BATCH * PH * PH * CH;

    pool_kernel<<<dim3(256, 8, 2), 256, 0, stream>>>(x1, x2, px);
    ycomp_kernel<<<dim3(57, 8, 2), 256, 0, stream>>>(px,
        conv3_w, conv3_b, bn3_g, bn3_b, bn3_m, bn3_v,
        conv4_w, conv4_b, bn4_g, bn4_b, bn4_m, bn4_v, y);
    attn_kernel<<<dim3(8), 256, 0, stream>>>(y, fc1_w, fc1_b, fc2_w, fc2_b,
        fc3_w1, fc3_b1, fc3_w2, fc3_b2, gates);
    prepack_kernel<<<dim3(4608), 256, 0, stream>>>(
        conv1_w, conv1_b, bn1_g, bn1_b, bn1_m, bn1_v,
        conv2_w, conv2_b, bn2_g, bn2_b, bn2_m, bn2_v, Wp, bias);
    pad_kernel<<<dim3(PH, 8, 2), 256, 0, stream>>>(x3, x4, xp3, xp4);

    // z=0: x3_out = x3 + gate1*BN1(conv1(x4)); z=1: x4_out = x4 + gate2*BN2(conv2(x3))
    conv_gemm<<<dim3(576, 2, 2), 256, 0, stream>>>(xp3, xp4, Wp, gates, bias,
        x3, x4, (float*)d_out);
}